// Round 13
// baseline (275.184 us; speedup 1.0000x reference)
//
#include <hip/hip_runtime.h>
#include <hip/hip_cooperative_groups.h>

namespace cg = cooperative_groups;

#define NPAIR 8192   // B*NCG

#define NCFG_REAL 5292
#define NCFG      5296
#define CPER      2646
#define WS_AT2F   0         // at2 table [7][128] (row 0 zeroed)
#define WS_TAB    1024      // tab [NCFG][128]
#define WS_NEED   ((size_t)(1024 + NCFG * 128) * 4)

#define COMP4(v, j) ((j) == 0 ? (v).x : (j) == 1 ? (v).y : (j) == 2 ? (v).z : (v).w)

__device__ __forceinline__ float sigmoidf_(float x) {
  return 1.0f / (1.0f + __expf(-x));
}

// ---- shared device body: table build (R11-proven) ----
__device__ __forceinline__ void build_tables(
    const float* __restrict__ init_emb, const float* __restrict__ other_emb,
    const float* __restrict__ op_embs,  const float* __restrict__ Wx,
    const float* __restrict__ bx,       const float* __restrict__ W1,
    const float* __restrict__ Wa1,      const float* __restrict__ ba1,
    const float* __restrict__ Wa2,      const float* __restrict__ ba2,
    float* __restrict__ ws,
    float* wsh, float* s1sh, float* at1sh, float* at2sh, float* y0, int t)
{
  // step 1: stage Wx -> wsh; embeddings -> at2sh
  for (int i = t; i < 576; i += 512) ((float4*)wsh)[i] = ((const float4*)Wx)[i];
  if (t < 48)       ((float4*)at2sh)[t] = ((const float4*)init_emb)[t];
  else if (t < 72)  ((float4*)at2sh)[t] = ((const float4*)other_emb)[t - 48];
  else if (t < 84)  ((float4*)at2sh)[t] = ((const float4*)bx)[t - 72];
  __syncthreads();

  // step 2: y0 = node @ Wx + bx
  for (int idx = t; idx < 576; idx += 512) {
    int c = idx / 288, i = (idx / 48) % 6, h = idx % 48;
    const float* nptr = (i < 2) ? (at2sh + (c * 2 + i) * 48)
                                : (at2sh + 192 + c * 48);
    float acc = at2sh[288 + h];
    for (int d = 0; d < 48; ++d) acc += nptr[d] * wsh[d * 48 + h];
    y0[idx] = acc;
  }
  __syncthreads();

  // step 3: stage W1 -> wsh; s1 = y0 @ W1
  for (int i = t; i < 1536; i += 512) ((float4*)wsh)[i] = ((const float4*)W1)[i];
  __syncthreads();
  for (int idx = t; idx < 1536; idx += 512) {
    int ci = idx >> 7, o = idx & 127;
    const float* yp = y0 + ci * 48;
    float acc = 0.f;
    for (int h = 0; h < 48; ++h) acc += yp[h] * wsh[h * 128 + o];
    s1sh[idx] = acc;
  }
  __syncthreads();

  // step 4: stage Wa1 -> wsh, op_embs -> y0; raw a1 -> at1sh
  for (int i = t; i < 1536; i += 512) ((float4*)wsh)[i] = ((const float4*)Wa1)[i];
  if (t < 84) ((float4*)y0)[t] = ((const float4*)op_embs)[t];
  __syncthreads();
  for (int idx = t; idx < 896; idx += 512) {
    int op = idx >> 7, o = idx & 127;
    float a = ba1[o];
    for (int d = 0; d < 48; ++d) a += y0[op * 48 + d] * wsh[d * 128 + o];
    at1sh[idx] = a;
  }
  __syncthreads();

  // step 5: stage Wa2 -> wsh; finalize both attn tables
  for (int i = t; i < 1536; i += 512) ((float4*)wsh)[i] = ((const float4*)Wa2)[i];
  __syncthreads();
  for (int idx = t; idx < 896; idx += 512) {
    int op = idx >> 7, o = idx & 127;
    float a2 = ba2[o];
    for (int d = 0; d < 48; ++d) a2 += y0[op * 48 + d] * wsh[d * 128 + o];
    float v1 = (op == 0) ? 0.f : sigmoidf_(at1sh[idx]);
    float v2 = (op == 0) ? 0.f : sigmoidf_(a2);
    at1sh[idx] = v1;
    at2sh[idx] = v2;
    ws[WS_AT2F + idx] = v2;   // identical from all blocks: benign
  }
  __syncthreads();
}

// ---- shared device body: per-pair gather/aggregate (R10/R11-proven) ----
__device__ __forceinline__ void gather_pair(
    const int* __restrict__ archs, const float* __restrict__ ws,
    float* __restrict__ out, int P, int o2)
{
  const int c = P & 1;
  const int* ap = archs + P * 16;     // wave-uniform -> scalar loads
  int f[8], op[8];
  #pragma unroll
  for (int e = 0; e < 8; ++e) { f[e] = ap[e]; op[e] = ap[8 + e]; }

  const float2* tab = (const float2*)(ws + WS_TAB);
  const float2* a2f = (const float2*)(ws + WS_AT2F);

  float2 S0 = tab[(NCFG_REAL + c * 2 + 0) * 64 + o2];
  float2 S1 = tab[(NCFG_REAL + c * 2 + 1) * 64 + o2];
  float2 S2, S3, S4, S5;
  {
    const int ib[4] = {0, 196, 637, 1421};
    #pragma unroll
    for (int i = 2; i < 6; ++i) {
      int e0 = 2 * (i - 2), e1 = e0 + 1;
      int cid = c * CPER + ib[i - 2] +
                ((f[e0] * 7 + op[e0]) * i + f[e1]) * 7 + op[e1];
      float2 v = tab[cid * 64 + o2];
      if (i == 2) S2 = v; else if (i == 3) S3 = v;
      else if (i == 4) S4 = v; else S5 = v;
    }
  }
  float2 A2[8];
  #pragma unroll
  for (int e = 0; e < 8; ++e) A2[e] = a2f[op[e] * 64 + o2];

  float r0 = S2.x + S3.x + S4.x + S5.x;
  float r1 = S2.y + S3.y + S4.y + S5.y;
  #pragma unroll
  for (int e = 0; e < 8; ++e) {
    int fe = f[e];
    float sx, sy;
    if (fe == 0)      { sx = S0.x; sy = S0.y; }
    else if (fe == 1) { sx = S1.x; sy = S1.y; }
    else if (fe == 2) { sx = S2.x; sy = S2.y; }
    else if (fe == 3) { sx = S3.x; sy = S3.y; }
    else              { sx = S4.x; sy = S4.y; }
    r0 += A2[e].x * sx;
    r1 += A2[e].y * sy;
  }
  ((float2*)out)[P * 64 + o2] = make_float2(r0 * 0.25f, r1 * 0.25f);
}

// ===================== PRIMARY: single cooperative kernel =====================
// 256 blocks x 512 thr (1 block/CU co-resident, LDS 48.4KB). Table build ->
// matvec (3 cfgs/wave over 2048 waves, 3x wider than R11's 83-block version)
// -> grid.sync (device-scope fence: cross-XCD tab visibility) -> gather
// 32 pairs/block. Removes one dispatch+gap vs R11's two-kernel path.
__global__ __launch_bounds__(512) void coop_kernel(
    const int*   __restrict__ archs,
    const float* __restrict__ init_emb, const float* __restrict__ other_emb,
    const float* __restrict__ op_embs,  const float* __restrict__ Wx,
    const float* __restrict__ bx,       const float* __restrict__ W1,
    const float* __restrict__ Wa1,      const float* __restrict__ ba1,
    const float* __restrict__ W2,       const float* __restrict__ Wa2,
    const float* __restrict__ ba2,      float* __restrict__ ws,
    float* __restrict__ out)
{
  __shared__ __align__(16) float wsh[8192];
  __shared__ __align__(16) float s1sh[1536];
  __shared__ __align__(16) float at1sh[896];
  __shared__ __align__(16) float at2sh[896];
  __shared__ __align__(16) float y0[576];
  const int t = threadIdx.x;

  build_tables(init_emb, other_emb, op_embs, Wx, bx, W1, Wa1, ba1, Wa2, ba2,
               ws, wsh, s1sh, at1sh, at2sh, y0, t);

  // ---- y1 for 3 configs per wave -> wsh ----
  const int w  = t >> 6, o2 = t & 63;
  const int wid  = blockIdx.x * 8 + w;        // 0..2047
  const int cfg0 = wid * 3;
  const float2* s1f = (const float2*)s1sh;
  const float2* a1f = (const float2*)at1sh;

  #pragma unroll
  for (int r = 0; r < 3; ++r) {
    int cfg = cfg0 + r;
    float2 v = make_float2(0.f, 0.f);
    if (cfg < NCFG_REAL) {
      int c = cfg / CPER, q = cfg % CPER;
      int i, b;
      if (q < 196)       { i = 2; b = 0; }
      else if (q < 637)  { i = 3; b = 196; }
      else if (q < 1421) { i = 4; b = 637; }
      else               { i = 5; b = 1421; }
      q -= b;
      int op2_ = q % 7; q /= 7;
      int f2_  = q % i; q /= i;
      int op1_ = q % 7;
      int f1_  = q / 7;
      int cb = c * 384;
      v = s1f[cb + i * 64 + o2];
      float2 A0 = a1f[op1_ * 64 + o2], B0 = s1f[cb + f1_ * 64 + o2];
      float2 A1 = a1f[op2_ * 64 + o2], B1 = s1f[cb + f2_ * 64 + o2];
      v.x += A0.x * B0.x + A1.x * B1.x;
      v.y += A0.y * B0.y + A1.y * B1.y;
    } else if (cfg < NCFG) {            // init-node pseudo-config
      int j = cfg - NCFG_REAL, c = j >> 1, i = j & 1;
      v = s1f[c * 384 + i * 64 + o2];
    }
    ((float2*)(wsh + (w * 3 + r) * 128))[o2] =
        make_float2(fmaxf(v.x, 0.f), fmaxf(v.y, 0.f));
  }
  __syncthreads();

  // ---- matvec: tab[cfg] = y1_cfg @ W2 ----
  const float* yb = wsh + (w * 3) * 128;
  const float2* W2f = (const float2*)W2;
  float2 acc[3];
  #pragma unroll
  for (int r = 0; r < 3; ++r) acc[r] = make_float2(0.f, 0.f);

  for (int k = 0; k < 128; k += 4) {
    float4 yv[3];
    #pragma unroll
    for (int r = 0; r < 3; ++r)
      yv[r] = *(const float4*)(yb + r * 128 + k);   // LDS broadcast
    #pragma unroll
    for (int j = 0; j < 4; ++j) {
      float2 wv = W2f[(k + j) * 64 + o2];
      #pragma unroll
      for (int r = 0; r < 3; ++r) {
        float y = COMP4(yv[r], j);
        acc[r].x += y * wv.x;
        acc[r].y += y * wv.y;
      }
    }
  }
  float2* tab = (float2*)(ws + WS_TAB);
  #pragma unroll
  for (int r = 0; r < 3; ++r) {
    int cfg = cfg0 + r;
    if (cfg < NCFG) tab[cfg * 64 + o2] = acc[r];
  }

  // ---- grid-wide barrier: tab complete & visible (device-scope fence) ----
  cg::this_grid().sync();

  // ---- gather: 32 pairs/block, 4 per wave ----
  #pragma unroll
  for (int k = 0; k < 4; ++k) {
    int P = blockIdx.x * 32 + w * 4 + k;
    gather_pair(archs, ws, out, P, o2);
  }
}

// ===================== FALLBACK 1: R11 two-kernel path =====================
__global__ __launch_bounds__(512) void config_kernel(
    const float* __restrict__ init_emb, const float* __restrict__ other_emb,
    const float* __restrict__ op_embs,  const float* __restrict__ Wx,
    const float* __restrict__ bx,       const float* __restrict__ W1,
    const float* __restrict__ Wa1,      const float* __restrict__ ba1,
    const float* __restrict__ W2,       const float* __restrict__ Wa2,
    const float* __restrict__ ba2,      float* __restrict__ ws)
{
  __shared__ __align__(16) float wsh[8192];
  __shared__ __align__(16) float s1sh[1536];
  __shared__ __align__(16) float at1sh[896];
  __shared__ __align__(16) float at2sh[896];
  __shared__ __align__(16) float y0[576];
  const int t = threadIdx.x;

  build_tables(init_emb, other_emb, op_embs, Wx, bx, W1, Wa1, ba1, Wa2, ba2,
               ws, wsh, s1sh, at1sh, at2sh, y0, t);

  const int w  = t >> 6, o2 = t & 63;
  const int cfg0 = (blockIdx.x * 8 + w) * 8;
  const float2* s1f = (const float2*)s1sh;
  const float2* a1f = (const float2*)at1sh;

  #pragma unroll
  for (int r = 0; r < 8; ++r) {
    int cfg = cfg0 + r;
    if (cfg >= NCFG) continue;
    float2 v;
    if (cfg < NCFG_REAL) {
      int c = cfg / CPER, q = cfg % CPER;
      int i, b;
      if (q < 196)       { i = 2; b = 0; }
      else if (q < 637)  { i = 3; b = 196; }
      else if (q < 1421) { i = 4; b = 637; }
      else               { i = 5; b = 1421; }
      q -= b;
      int op2_ = q % 7; q /= 7;
      int f2_  = q % i; q /= i;
      int op1_ = q % 7;
      int f1_  = q / 7;
      int cb = c * 384;
      v = s1f[cb + i * 64 + o2];
      float2 A0 = a1f[op1_ * 64 + o2], B0 = s1f[cb + f1_ * 64 + o2];
      float2 A1 = a1f[op2_ * 64 + o2], B1 = s1f[cb + f2_ * 64 + o2];
      v.x += A0.x * B0.x + A1.x * B1.x;
      v.y += A0.y * B0.y + A1.y * B1.y;
    } else {
      int j = cfg - NCFG_REAL, c = j >> 1, i = j & 1;
      v = s1f[c * 384 + i * 64 + o2];
    }
    ((float2*)(wsh + (w * 8 + r) * 128))[o2] =
        make_float2(fmaxf(v.x, 0.f), fmaxf(v.y, 0.f));
  }
  __syncthreads();

  const float* yb = wsh + (w * 8) * 128;
  const float2* W2f = (const float2*)W2;
  float2 acc[8];
  #pragma unroll
  for (int r = 0; r < 8; ++r) acc[r] = make_float2(0.f, 0.f);
  for (int k = 0; k < 128; k += 4) {
    float4 yv[8];
    #pragma unroll
    for (int r = 0; r < 8; ++r)
      yv[r] = *(const float4*)(yb + r * 128 + k);
    #pragma unroll
    for (int j = 0; j < 4; ++j) {
      float2 wv = W2f[(k + j) * 64 + o2];
      #pragma unroll
      for (int r = 0; r < 8; ++r) {
        float y = COMP4(yv[r], j);
        acc[r].x += y * wv.x;
        acc[r].y += y * wv.y;
      }
    }
  }
  float2* tab = (float2*)(ws + WS_TAB);
  #pragma unroll
  for (int r = 0; r < 8; ++r) {
    int cfg = cfg0 + r;
    if (cfg < NCFG) tab[cfg * 64 + o2] = acc[r];
  }
}

__global__ __launch_bounds__(256) void gather_kernel(
    const int* __restrict__ archs, const float* __restrict__ ws,
    float* __restrict__ out)
{
  const int t  = threadIdx.x;
  const int pp = t >> 6;
  const int o2 = t & 63;
  const int P  = blockIdx.x * 4 + pp;
  gather_pair(archs, ws, out, P, o2);
}

extern "C" void kernel_launch(void* const* d_in, const int* in_sizes, int n_in,
                              void* d_out, int out_size, void* d_ws, size_t ws_size,
                              hipStream_t stream) {
  const int*   archs    = (const int*)d_in[0];
  const float* init_emb = (const float*)d_in[1];
  const float* other_e  = (const float*)d_in[2];
  const float* op_embs  = (const float*)d_in[3];
  const float* Wx       = (const float*)d_in[4];
  const float* bx       = (const float*)d_in[5];
  const float* W1       = (const float*)d_in[6];
  const float* Wa1      = (const float*)d_in[7];
  const float* ba1      = (const float*)d_in[8];
  const float* W2       = (const float*)d_in[9];
  const float* Wa2      = (const float*)d_in[10];
  const float* ba2      = (const float*)d_in[11];
  float* ws   = (float*)d_ws;
  float* outp = (float*)d_out;

  void* args[] = {
    (void*)&archs, (void*)&init_emb, (void*)&other_e, (void*)&op_embs,
    (void*)&Wx, (void*)&bx, (void*)&W1, (void*)&Wa1, (void*)&ba1,
    (void*)&W2, (void*)&Wa2, (void*)&ba2, (void*)&ws, (void*)&outp
  };
  hipError_t err = hipLaunchCooperativeKernel(
      reinterpret_cast<void*>(coop_kernel), dim3(256), dim3(512), args, 0, stream);
  if (err != hipSuccess) {
    // deterministic fallback: R11's proven two-kernel path
    config_kernel<<<83, 512, 0, stream>>>(
        init_emb, other_e, op_embs, Wx, bx, W1, Wa1, ba1, W2, Wa2, ba2, ws);
    gather_kernel<<<NPAIR / 4, 256, 0, stream>>>(archs, ws, outp);
  }
}

// Round 14
// 251.103 us; speedup vs baseline: 1.0959x; 1.0959x over previous
//
#include <hip/hip_runtime.h>

#define NPAIR 8192   // B*NCG

// ===================== config-deduplicated path (R11-proven) ==============
// Node layer-1 output depends only on (c, i, f_s0, op_s0, f_s1, op_s1):
// 5292 real configs + 4 init pseudo-rows. config_kernel builds tab[cfg] =
// relu(y1_cfg) @ W2; gather_kernel is a pure table gather/aggregate.
// R13 lesson: cooperative fusion (grid.sync) costs ~150MB of coherence/spill
// traffic -- keep the two-kernel split. R14 tweak: matvec widened to 166
// blocks x 4 cfgs/wave (halves per-wave VALU + register pressure vs 83x8).
#define NCFG_REAL 5292
#define NCFG      5296
#define CPER      2646
#define WS_AT2F   0         // at2 table [7][128] (row 0 zeroed)
#define WS_TAB    1024      // tab [NCFG][128]
#define WS_NEED   ((size_t)(1024 + NCFG * 128) * 4)

#define COMP4(v, j) ((j) == 0 ? (v).x : (j) == 1 ? (v).y : (j) == 2 ? (v).z : (v).w)

__device__ __forceinline__ float sigmoidf_(float x) {
  return 1.0f / (1.0f + __expf(-x));
}

__global__ __launch_bounds__(512) void config_kernel(
    const float* __restrict__ init_emb, const float* __restrict__ other_emb,
    const float* __restrict__ op_embs,  const float* __restrict__ Wx,
    const float* __restrict__ bx,       const float* __restrict__ W1,
    const float* __restrict__ Wa1,      const float* __restrict__ ba1,
    const float* __restrict__ W2,       const float* __restrict__ Wa2,
    const float* __restrict__ ba2,      float* __restrict__ ws)
{
  __shared__ __align__(16) float wsh[8192];   // weight staging, then y1 store
  __shared__ __align__(16) float s1sh[1536];  // support1 [2][6][128]
  __shared__ __align__(16) float at1sh[896];  // [7][128] row0=0
  __shared__ __align__(16) float at2sh[896];  // embeddings scratch, then at2
  __shared__ __align__(16) float y0[576];     // y0, then op_embs scratch
  const int t = threadIdx.x;

  // ---- step 1: stage Wx (2304 f) -> wsh; embeddings (336 f) -> at2sh ----
  for (int i = t; i < 576; i += 512) ((float4*)wsh)[i] = ((const float4*)Wx)[i];
  if (t < 48)       ((float4*)at2sh)[t] = ((const float4*)init_emb)[t];
  else if (t < 72)  ((float4*)at2sh)[t] = ((const float4*)other_emb)[t - 48];
  else if (t < 84)  ((float4*)at2sh)[t] = ((const float4*)bx)[t - 72];
  __syncthreads();

  // ---- step 2: y0[c][i][h] = node @ Wx + bx (all LDS operands) ----
  for (int idx = t; idx < 576; idx += 512) {
    int c = idx / 288, i = (idx / 48) % 6, h = idx % 48;
    const float* nptr = (i < 2) ? (at2sh + (c * 2 + i) * 48)
                                : (at2sh + 192 + c * 48);
    float acc = at2sh[288 + h];
    for (int d = 0; d < 48; ++d) acc += nptr[d] * wsh[d * 48 + h];
    y0[idx] = acc;
  }
  __syncthreads();

  // ---- step 3: stage W1 (6144 f) -> wsh; s1 = y0 @ W1 ----
  for (int i = t; i < 1536; i += 512) ((float4*)wsh)[i] = ((const float4*)W1)[i];
  __syncthreads();
  for (int idx = t; idx < 1536; idx += 512) {
    int ci = idx >> 7, o = idx & 127;
    const float* yp = y0 + ci * 48;
    float acc = 0.f;
    for (int h = 0; h < 48; ++h) acc += yp[h] * wsh[h * 128 + o];
    s1sh[idx] = acc;
  }
  __syncthreads();   // y0 free, W1 readers done

  // ---- step 4: stage Wa1 -> wsh, op_embs (336 f) -> y0; a1 raw -> at1sh ---
  for (int i = t; i < 1536; i += 512) ((float4*)wsh)[i] = ((const float4*)Wa1)[i];
  if (t < 84) ((float4*)y0)[t] = ((const float4*)op_embs)[t];
  __syncthreads();
  for (int idx = t; idx < 896; idx += 512) {
    int op = idx >> 7, o = idx & 127;
    float a = ba1[o];
    for (int d = 0; d < 48; ++d) a += y0[op * 48 + d] * wsh[d * 128 + o];
    at1sh[idx] = a;                    // raw; sigmoid in step 5
  }
  __syncthreads();

  // ---- step 5: stage Wa2 -> wsh; a2, sigmoid both, finalize tables ----
  for (int i = t; i < 1536; i += 512) ((float4*)wsh)[i] = ((const float4*)Wa2)[i];
  __syncthreads();
  for (int idx = t; idx < 896; idx += 512) {
    int op = idx >> 7, o = idx & 127;
    float a2 = ba2[o];
    for (int d = 0; d < 48; ++d) a2 += y0[op * 48 + d] * wsh[d * 128 + o];
    float v1 = (op == 0) ? 0.f : sigmoidf_(at1sh[idx]);   // NONE mask baked in
    float v2 = (op == 0) ? 0.f : sigmoidf_(a2);
    at1sh[idx] = v1;
    at2sh[idx] = v2;                   // overwrites embedding scratch (dead)
    ws[WS_AT2F + idx] = v2;            // identical from all blocks: benign
  }
  __syncthreads();

  // ---- step 6: per-wave 4 configs -> relu(y1) into wsh ----
  const int w  = t >> 6, o2 = t & 63;
  const int cfg0 = (blockIdx.x * 8 + w) * 4;
  const float2* s1f = (const float2*)s1sh;    // [12][64]
  const float2* a1f = (const float2*)at1sh;   // [7][64]

  #pragma unroll
  for (int r = 0; r < 4; ++r) {
    int cfg = cfg0 + r;
    if (cfg >= NCFG) continue;
    float2 v;
    if (cfg < NCFG_REAL) {
      int c = cfg / CPER, q = cfg % CPER;
      int i, b;
      if (q < 196)       { i = 2; b = 0; }
      else if (q < 637)  { i = 3; b = 196; }
      else if (q < 1421) { i = 4; b = 637; }
      else               { i = 5; b = 1421; }
      q -= b;
      int op2_ = q % 7; q /= 7;
      int f2_  = q % i; q /= i;
      int op1_ = q % 7;
      int f1_  = q / 7;
      int cb = c * 384;
      v = s1f[cb + i * 64 + o2];
      float2 A0 = a1f[op1_ * 64 + o2], B0 = s1f[cb + f1_ * 64 + o2];
      float2 A1 = a1f[op2_ * 64 + o2], B1 = s1f[cb + f2_ * 64 + o2];
      v.x += A0.x * B0.x + A1.x * B1.x;
      v.y += A0.y * B0.y + A1.y * B1.y;
    } else {                           // init node pseudo-config (no in-edges)
      int j = cfg - NCFG_REAL, c = j >> 1, i = j & 1;
      v = s1f[c * 384 + i * 64 + o2];
    }
    ((float2*)(wsh + (w * 4 + r) * 128))[o2] =
        make_float2(fmaxf(v.x, 0.f), fmaxf(v.y, 0.f));
  }
  __syncthreads();

  // ---- step 7: tab[cfg] = y1_cfg @ W2 (W2 global, L1-hot) ----
  const float* yb = wsh + (w * 4) * 128;
  const float2* W2f = (const float2*)W2;
  float2 acc[4];
  #pragma unroll
  for (int r = 0; r < 4; ++r) acc[r] = make_float2(0.f, 0.f);

  for (int k = 0; k < 128; k += 4) {
    float4 yv[4];
    #pragma unroll
    for (int r = 0; r < 4; ++r)
      yv[r] = *(const float4*)(yb + r * 128 + k);
    #pragma unroll
    for (int j = 0; j < 4; ++j) {
      float2 wv = W2f[(k + j) * 64 + o2];
      #pragma unroll
      for (int r = 0; r < 4; ++r) {
        float y = COMP4(yv[r], j);
        acc[r].x += y * wv.x;
        acc[r].y += y * wv.y;
      }
    }
  }

  float2* tab = (float2*)(ws + WS_TAB);
  #pragma unroll
  for (int r = 0; r < 4; ++r) {
    int cfg = cfg0 + r;
    if (cfg < NCFG) tab[cfg * 64 + o2] = acc[r];
  }
}

__global__ __launch_bounds__(256) void gather_kernel(
    const int* __restrict__ archs, const float* __restrict__ ws,
    float* __restrict__ out)
{
  const int t  = threadIdx.x;
  const int pp = t >> 6;
  const int o2 = t & 63;
  const int P  = blockIdx.x * 4 + pp;
  const int c  = P & 1;

  __shared__ int archsh[64];
  if (t < 64) archsh[t] = archs[blockIdx.x * 64 + t];
  __syncthreads();

  int f[8], op[8];
  #pragma unroll
  for (int e = 0; e < 8; ++e) { f[e] = archsh[pp * 16 + e]; op[e] = archsh[pp * 16 + 8 + e]; }

  const float2* tab = (const float2*)(ws + WS_TAB);
  const float2* a2f = (const float2*)(ws + WS_AT2F);

  float2 S0 = tab[(NCFG_REAL + c * 2 + 0) * 64 + o2];
  float2 S1 = tab[(NCFG_REAL + c * 2 + 1) * 64 + o2];
  float2 S2, S3, S4, S5;
  {
    const int ib[4] = {0, 196, 637, 1421};
    #pragma unroll
    for (int i = 2; i < 6; ++i) {
      int e0 = 2 * (i - 2), e1 = e0 + 1;
      int cid = c * CPER + ib[i - 2] +
                ((f[e0] * 7 + op[e0]) * i + f[e1]) * 7 + op[e1];
      float2 v = tab[cid * 64 + o2];
      if (i == 2) S2 = v; else if (i == 3) S3 = v;
      else if (i == 4) S4 = v; else S5 = v;
    }
  }
  float2 A2[8];
  #pragma unroll
  for (int e = 0; e < 8; ++e) A2[e] = a2f[op[e] * 64 + o2];

  float r0 = S2.x + S3.x + S4.x + S5.x;
  float r1 = S2.y + S3.y + S4.y + S5.y;
  #pragma unroll
  for (int e = 0; e < 8; ++e) {
    int fe = f[e];
    float sx, sy;
    if (fe == 0)      { sx = S0.x; sy = S0.y; }
    else if (fe == 1) { sx = S1.x; sy = S1.y; }
    else if (fe == 2) { sx = S2.x; sy = S2.y; }
    else if (fe == 3) { sx = S3.x; sy = S3.y; }
    else              { sx = S4.x; sy = S4.y; }
    r0 += A2[e].x * sx;
    r1 += A2[e].y * sy;
  }
  ((float2*)out)[P * 64 + o2] = make_float2(r0 * 0.25f, r1 * 0.25f);
}

// ===================== FALLBACK: R9 verbatim (if ws too small) ============
#define FB_S1   0
#define FB_AT1  1536
#define FB_AT2  2432
#define FB_S2I  3328

__global__ __launch_bounds__(512) void precompute_kernel(
    const float* __restrict__ init_emb, const float* __restrict__ other_emb,
    const float* __restrict__ op_embs,  const float* __restrict__ Wx,
    const float* __restrict__ bx,       const float* __restrict__ W1,
    const float* __restrict__ Wa1,      const float* __restrict__ ba1,
    const float* __restrict__ W2,       const float* __restrict__ Wa2,
    const float* __restrict__ ba2,      float* __restrict__ ws)
{
  const int t   = threadIdx.x;
  const int blk = blockIdx.x;
  __shared__ float y0[576];
  __shared__ float s1sh[1536];
  for (int idx = t; idx < 576; idx += 512) {
    int c = idx / 288, i = (idx / 48) % 6, h = idx % 48;
    const float* nptr = (i < 2) ? (init_emb + (c * 2 + i) * 48)
                                : (other_emb + c * 48);
    float acc = bx[h];
    for (int d = 0; d < 48; ++d) acc += nptr[d] * Wx[d * 48 + h];
    y0[idx] = acc;
  }
  __syncthreads();
  for (int idx = t; idx < 1536; idx += 512) {
    int ci = idx >> 7, o = idx & 127;
    const float* yp = y0 + ci * 48;
    float acc = 0.f;
    for (int h = 0; h < 48; ++h) acc += yp[h] * W1[h * 128 + o];
    s1sh[idx] = acc;
    ws[FB_S1 + idx] = acc;
  }
  for (int idx = blk * 112 + t; idx < (blk + 1) * 112; idx += 512) {
    int op = idx >> 7, o = idx & 127;
    float a1 = ba1[o], a2 = ba2[o];
    for (int d = 0; d < 48; ++d) {
      float e = op_embs[op * 48 + d];
      a1 += e * Wa1[d * 128 + o];
      a2 += e * Wa2[d * 128 + o];
    }
    ws[FB_AT1 + idx] = (op == 0) ? 0.f : sigmoidf_(a1);
    ws[FB_AT2 + idx] = (op == 0) ? 0.f : sigmoidf_(a2);
  }
  __syncthreads();
  for (int idx = blk * 64 + t; idx < (blk + 1) * 64; idx += 512) {
    int c = idx >> 8, i = (idx >> 7) & 1, o = idx & 127;
    const float* sp = s1sh + (c * 6 + i) * 128;
    float acc = 0.f;
    for (int h = 0; h < 128; ++h) acc += fmaxf(sp[h], 0.f) * W2[h * 128 + o];
    ws[FB_S2I + idx] = acc;
  }
}

__global__ __launch_bounds__(256) void main_kernel(
    const int* __restrict__ archs, const float* __restrict__ W2,
    const float* __restrict__ ws, float* __restrict__ out)
{
  const int t  = threadIdx.x;
  const int pp = t >> 6;
  const int o2 = t & 63;
  const int P  = blockIdx.x * 4 + pp;
  const int c  = P & 1;
  __shared__ float y1sh[4][512];
  __shared__ int   archsh[64];
  if (t < 64) archsh[t] = archs[blockIdx.x * 64 + t];
  __syncthreads();
  int f[8], op[8];
  #pragma unroll
  for (int e = 0; e < 8; ++e) { f[e] = archsh[pp * 16 + e]; op[e] = archsh[pp * 16 + 8 + e]; }
  const float2* s1p = (const float2*)ws + c * 384;
  const float2* at1 = (const float2*)(ws + FB_AT1);
  const float2* at2 = (const float2*)(ws + FB_AT2);
  const float2* s2i = (const float2*)(ws + FB_S2I) + c * 128;
  float2 A2[8];
  #pragma unroll
  for (int e = 0; e < 8; ++e) A2[e] = at2[op[e] * 64 + o2];
  float2 S0 = s2i[o2], S1 = s2i[64 + o2];
  #pragma unroll
  for (int i = 0; i < 4; ++i) {
    float2 v = s1p[(2 + i) * 64 + o2];
    int e0 = 2 * i, e1 = 2 * i + 1;
    float2 A0 = at1[op[e0] * 64 + o2];
    float2 B0 = s1p[f[e0] * 64 + o2];
    float2 A1 = at1[op[e1] * 64 + o2];
    float2 B1 = s1p[f[e1] * 64 + o2];
    v.x += A0.x * B0.x + A1.x * B1.x;
    v.y += A0.y * B0.y + A1.y * B1.y;
    ((float2*)(y1sh[pp] + i * 128))[o2] =
        make_float2(fmaxf(v.x, 0.f), fmaxf(v.y, 0.f));
  }
  __syncthreads();
  const float* y1p = y1sh[pp];
  const float2* W2f = (const float2*)W2;
  float ax0 = 0, ax1 = 0, ax2 = 0, ax3 = 0;
  float ay0 = 0, ay1 = 0, ay2 = 0, ay3 = 0;
  for (int h = 0; h < 128; h += 4) {
    float4 q0 = *(const float4*)(y1p + 0 * 128 + h);
    float4 q1 = *(const float4*)(y1p + 1 * 128 + h);
    float4 q2 = *(const float4*)(y1p + 2 * 128 + h);
    float4 q3 = *(const float4*)(y1p + 3 * 128 + h);
    #pragma unroll
    for (int j = 0; j < 4; ++j) {
      float2 wf = W2f[(h + j) * 64 + o2];
      float w0 = wf.x, w1 = wf.y, y;
      y = COMP4(q0, j); ax0 += y * w0; ay0 += y * w1;
      y = COMP4(q1, j); ax1 += y * w0; ay1 += y * w1;
      y = COMP4(q2, j); ax2 += y * w0; ay2 += y * w1;
      y = COMP4(q3, j); ax3 += y * w0; ay3 += y * w1;
    }
  }
  float r0 = ax0 + ax1 + ax2 + ax3;
  float r1 = ay0 + ay1 + ay2 + ay3;
  #pragma unroll
  for (int e = 0; e < 8; ++e) {
    int fe = f[e];
    float sx, sy;
    if (fe == 0)      { sx = S0.x; sy = S0.y; }
    else if (fe == 1) { sx = S1.x; sy = S1.y; }
    else if (fe == 2) { sx = ax0; sy = ay0; }
    else if (fe == 3) { sx = ax1; sy = ay1; }
    else if (fe == 4) { sx = ax2; sy = ay2; }
    else              { sx = ax3; sy = ay3; }
    r0 += A2[e].x * sx;
    r1 += A2[e].y * sy;
  }
  ((float2*)out)[P * 64 + o2] = make_float2(r0 * 0.25f, r1 * 0.25f);
}

extern "C" void kernel_launch(void* const* d_in, const int* in_sizes, int n_in,
                              void* d_out, int out_size, void* d_ws, size_t ws_size,
                              hipStream_t stream) {
  const int* archs = (const int*)d_in[0];
  float* ws = (float*)d_ws;
  if (ws_size >= WS_NEED) {
    config_kernel<<<166, 512, 0, stream>>>(
        (const float*)d_in[1], (const float*)d_in[2], (const float*)d_in[3],
        (const float*)d_in[4], (const float*)d_in[5], (const float*)d_in[6],
        (const float*)d_in[7], (const float*)d_in[8], (const float*)d_in[9],
        (const float*)d_in[10], (const float*)d_in[11], ws);
    gather_kernel<<<NPAIR / 4, 256, 0, stream>>>(archs, ws, (float*)d_out);
  } else {
    precompute_kernel<<<8, 512, 0, stream>>>(
        (const float*)d_in[1], (const float*)d_in[2], (const float*)d_in[3],
        (const float*)d_in[4], (const float*)d_in[5], (const float*)d_in[6],
        (const float*)d_in[7], (const float*)d_in[8], (const float*)d_in[9],
        (const float*)d_in[10], (const float*)d_in[11], ws);
    main_kernel<<<NPAIR / 4, 256, 0, stream>>>(archs, (const float*)d_in[9], ws,
                                               (float*)d_out);
  }
}

// Round 16
// 103.106 us; speedup vs baseline: 2.6689x; 2.4354x over previous
//
#include <hip/hip_runtime.h>

#define NPAIR 8192   // B*NCG

// ===================== config-deduplicated path =====================
// Node layer-1 output depends only on (c, i, f_s0, op_s0, f_s1, op_s1):
// 5292 real configs + 4 init pseudo-rows = 5296. config_kernel builds
// tab[cfg] = relu(y1_cfg) @ W2; gather_kernel is a pure gather/aggregate.
// R14 forensics: 512-thread kernels with indexed acc[]/yv[] register arrays
// get VGPR-capped at 128 and the arrays land in scratch (135MB FETCH /
// 137MB WRITE, VALUBusy 2.5%). Fix: 256 threads, 4 waves x 4 configs,
// matvec with SCALAR accumulators -- the exact R5/R9 shape (VGPR 56-68,
// zero spill, session-proven).
#define NCFG_REAL 5292
#define NCFG      5296
#define CPER      2646
#define WS_AT2F   0         // at2 table [7][128] (row 0 zeroed)
#define WS_TAB    1024      // tab [NCFG][128]
#define WS_NEED   ((size_t)(1024 + NCFG * 128) * 4)

#define COMP4(v, j) ((j) == 0 ? (v).x : (j) == 1 ? (v).y : (j) == 2 ? (v).z : (v).w)

__device__ __forceinline__ float sigmoidf_(float x) {
  return 1.0f / (1.0f + __expf(-x));
}

// 331 blocks x 256 threads; 16 configs per block (331*16 = 5296 exact).
__global__ __launch_bounds__(256) void config_kernel(
    const float* __restrict__ init_emb, const float* __restrict__ other_emb,
    const float* __restrict__ op_embs,  const float* __restrict__ Wx,
    const float* __restrict__ bx,       const float* __restrict__ W1,
    const float* __restrict__ Wa1,      const float* __restrict__ ba1,
    const float* __restrict__ W2,       const float* __restrict__ Wa2,
    const float* __restrict__ ba2,      float* __restrict__ ws)
{
  __shared__ __align__(16) float wsh[6144];   // weight staging; later y1 [4][4][128]
  __shared__ __align__(16) float s1sh[1536];  // support1 [2][6][128]
  __shared__ __align__(16) float at1sh[896];  // [7][128] row0=0
  __shared__ __align__(16) float at2sh[896];  // embeddings scratch, then at2
  __shared__ __align__(16) float y0[576];     // y0, then op_embs scratch
  const int t = threadIdx.x;

  // ---- step 1: stage Wx (576 float4) -> wsh; embeddings (84 f4) -> at2sh --
  for (int i = t; i < 576; i += 256) ((float4*)wsh)[i] = ((const float4*)Wx)[i];
  if (t < 48)       ((float4*)at2sh)[t] = ((const float4*)init_emb)[t];
  else if (t < 72)  ((float4*)at2sh)[t] = ((const float4*)other_emb)[t - 48];
  else if (t < 84)  ((float4*)at2sh)[t] = ((const float4*)bx)[t - 72];
  __syncthreads();

  // ---- step 2: y0[c][i][h] = node @ Wx + bx (all LDS operands) ----
  for (int idx = t; idx < 576; idx += 256) {
    int c = idx / 288, i = (idx / 48) % 6, h = idx % 48;
    const float* nptr = (i < 2) ? (at2sh + (c * 2 + i) * 48)
                                : (at2sh + 192 + c * 48);
    float acc = at2sh[288 + h];
    for (int d = 0; d < 48; ++d) acc += nptr[d] * wsh[d * 48 + h];
    y0[idx] = acc;
  }
  __syncthreads();

  // ---- step 3: stage W1 (1536 float4) -> wsh; s1 = y0 @ W1 ----
  for (int i = t; i < 1536; i += 256) ((float4*)wsh)[i] = ((const float4*)W1)[i];
  __syncthreads();
  for (int idx = t; idx < 1536; idx += 256) {
    int ci = idx >> 7, o = idx & 127;
    const float* yp = y0 + ci * 48;
    float acc = 0.f;
    for (int h = 0; h < 48; ++h) acc += yp[h] * wsh[h * 128 + o];
    s1sh[idx] = acc;
  }
  __syncthreads();   // y0 free, W1 readers done

  // ---- step 4: stage Wa1 -> wsh, op_embs (84 f4) -> y0; raw a1 -> at1sh ---
  for (int i = t; i < 1536; i += 256) ((float4*)wsh)[i] = ((const float4*)Wa1)[i];
  if (t < 84) ((float4*)y0)[t] = ((const float4*)op_embs)[t];
  __syncthreads();
  for (int idx = t; idx < 896; idx += 256) {
    int op = idx >> 7, o = idx & 127;
    float a = ba1[o];
    for (int d = 0; d < 48; ++d) a += y0[op * 48 + d] * wsh[d * 128 + o];
    at1sh[idx] = a;                    // raw; sigmoid in step 5
  }
  __syncthreads();

  // ---- step 5: stage Wa2 -> wsh; a2, sigmoid both, finalize tables ----
  for (int i = t; i < 1536; i += 256) ((float4*)wsh)[i] = ((const float4*)Wa2)[i];
  __syncthreads();
  for (int idx = t; idx < 896; idx += 256) {
    int op = idx >> 7, o = idx & 127;
    float a2 = ba2[o];
    for (int d = 0; d < 48; ++d) a2 += y0[op * 48 + d] * wsh[d * 128 + o];
    float v1 = (op == 0) ? 0.f : sigmoidf_(at1sh[idx]);   // NONE mask baked in
    float v2 = (op == 0) ? 0.f : sigmoidf_(a2);
    at1sh[idx] = v1;
    at2sh[idx] = v2;                   // overwrites embedding scratch (dead)
    ws[WS_AT2F + idx] = v2;            // identical from all blocks: benign
  }
  __syncthreads();                     // wsh (Wa2) readers done -> y1 overlay ok

  // ---- step 6: wave w -> 4 configs, y1 rows into wsh[w*512 ..] ----
  const int w  = t >> 6, o2 = t & 63;
  const int cfg0 = blockIdx.x * 16 + w * 4;   // 331*16 = 5296: no overflow
  const float2* s1f = (const float2*)s1sh;    // [12][64]
  const float2* a1f = (const float2*)at1sh;   // [7][64]
  float* y1p = wsh + w * 512;                 // [4 configs][128]

  #pragma unroll
  for (int r = 0; r < 4; ++r) {
    int cfg = cfg0 + r;
    float2 v;
    if (cfg < NCFG_REAL) {
      int c = cfg / CPER, q = cfg % CPER;
      int i, b;
      if (q < 196)       { i = 2; b = 0; }
      else if (q < 637)  { i = 3; b = 196; }
      else if (q < 1421) { i = 4; b = 637; }
      else               { i = 5; b = 1421; }
      q -= b;
      int op2_ = q % 7; q /= 7;
      int f2_  = q % i; q /= i;
      int op1_ = q % 7;
      int f1_  = q / 7;
      int cb = c * 384;
      v = s1f[cb + i * 64 + o2];
      float2 A0 = a1f[op1_ * 64 + o2], B0 = s1f[cb + f1_ * 64 + o2];
      float2 A1 = a1f[op2_ * 64 + o2], B1 = s1f[cb + f2_ * 64 + o2];
      v.x += A0.x * B0.x + A1.x * B1.x;
      v.y += A0.y * B0.y + A1.y * B1.y;
    } else {                           // init node pseudo-config (no in-edges)
      int j = cfg - NCFG_REAL, c = j >> 1, i = j & 1;
      v = s1f[c * 384 + i * 64 + o2];
    }
    ((float2*)(y1p + r * 128))[o2] =
        make_float2(fmaxf(v.x, 0.f), fmaxf(v.y, 0.f));
  }
  __syncthreads();

  // ---- step 7: tab rows = y1 @ W2 -- R5/R9-proven scalar-accumulator gemm --
  const float2* W2f = (const float2*)W2;
  float ax0 = 0, ax1 = 0, ax2 = 0, ax3 = 0;
  float ay0 = 0, ay1 = 0, ay2 = 0, ay3 = 0;

  for (int h = 0; h < 128; h += 4) {
    float4 q0 = *(const float4*)(y1p + 0 * 128 + h);  // wave-broadcast LDS
    float4 q1 = *(const float4*)(y1p + 1 * 128 + h);
    float4 q2 = *(const float4*)(y1p + 2 * 128 + h);
    float4 q3 = *(const float4*)(y1p + 3 * 128 + h);
    #pragma unroll
    for (int j = 0; j < 4; ++j) {
      float2 wf = W2f[(h + j) * 64 + o2];
      float w0 = wf.x, w1 = wf.y, y;
      y = COMP4(q0, j); ax0 += y * w0; ay0 += y * w1;
      y = COMP4(q1, j); ax1 += y * w0; ay1 += y * w1;
      y = COMP4(q2, j); ax2 += y * w0; ay2 += y * w1;
      y = COMP4(q3, j); ax3 += y * w0; ay3 += y * w1;
    }
  }

  float2* tab = (float2*)(ws + WS_TAB);
  tab[(cfg0 + 0) * 64 + o2] = make_float2(ax0, ay0);
  tab[(cfg0 + 1) * 64 + o2] = make_float2(ax1, ay1);
  tab[(cfg0 + 2) * 64 + o2] = make_float2(ax2, ay2);
  tab[(cfg0 + 3) * 64 + o2] = make_float2(ax3, ay3);
}

__global__ __launch_bounds__(256) void gather_kernel(
    const int* __restrict__ archs, const float* __restrict__ ws,
    float* __restrict__ out)
{
  const int t  = threadIdx.x;
  const int pp = t >> 6;
  const int o2 = t & 63;
  const int P  = blockIdx.x * 4 + pp;
  const int c  = P & 1;

  __shared__ int archsh[64];
  if (t < 64) archsh[t] = archs[blockIdx.x * 64 + t];
  __syncthreads();

  int f[8], op[8];
  #pragma unroll
  for (int e = 0; e < 8; ++e) { f[e] = archsh[pp * 16 + e]; op[e] = archsh[pp * 16 + 8 + e]; }

  const float2* tab = (const float2*)(ws + WS_TAB);
  const float2* a2f = (const float2*)(ws + WS_AT2F);

  float2 S0 = tab[(NCFG_REAL + c * 2 + 0) * 64 + o2];
  float2 S1 = tab[(NCFG_REAL + c * 2 + 1) * 64 + o2];
  float2 S2, S3, S4, S5;
  {
    const int ib[4] = {0, 196, 637, 1421};
    #pragma unroll
    for (int i = 2; i < 6; ++i) {
      int e0 = 2 * (i - 2), e1 = e0 + 1;
      int cid = c * CPER + ib[i - 2] +
                ((f[e0] * 7 + op[e0]) * i + f[e1]) * 7 + op[e1];
      float2 v = tab[cid * 64 + o2];
      if (i == 2) S2 = v; else if (i == 3) S3 = v;
      else if (i == 4) S4 = v; else S5 = v;
    }
  }
  float2 A2[8];
  #pragma unroll
  for (int e = 0; e < 8; ++e) A2[e] = a2f[op[e] * 64 + o2];

  float r0 = S2.x + S3.x + S4.x + S5.x;
  float r1 = S2.y + S3.y + S4.y + S5.y;
  #pragma unroll
  for (int e = 0; e < 8; ++e) {
    int fe = f[e];
    float sx, sy;
    if (fe == 0)      { sx = S0.x; sy = S0.y; }
    else if (fe == 1) { sx = S1.x; sy = S1.y; }
    else if (fe == 2) { sx = S2.x; sy = S2.y; }
    else if (fe == 3) { sx = S3.x; sy = S3.y; }
    else              { sx = S4.x; sy = S4.y; }
    r0 += A2[e].x * sx;
    r1 += A2[e].y * sy;
  }
  ((float2*)out)[P * 64 + o2] = make_float2(r0 * 0.25f, r1 * 0.25f);
}

// ===================== FALLBACK: R9 verbatim (if ws too small) ============
#define FB_S1   0
#define FB_AT1  1536
#define FB_AT2  2432
#define FB_S2I  3328

__global__ __launch_bounds__(512) void precompute_kernel(
    const float* __restrict__ init_emb, const float* __restrict__ other_emb,
    const float* __restrict__ op_embs,  const float* __restrict__ Wx,
    const float* __restrict__ bx,       const float* __restrict__ W1,
    const float* __restrict__ Wa1,      const float* __restrict__ ba1,
    const float* __restrict__ W2,       const float* __restrict__ Wa2,
    const float* __restrict__ ba2,      float* __restrict__ ws)
{
  const int t   = threadIdx.x;
  const int blk = blockIdx.x;
  __shared__ float y0[576];
  __shared__ float s1sh[1536];
  for (int idx = t; idx < 576; idx += 512) {
    int c = idx / 288, i = (idx / 48) % 6, h = idx % 48;
    const float* nptr = (i < 2) ? (init_emb + (c * 2 + i) * 48)
                                : (other_emb + c * 48);
    float acc = bx[h];
    for (int d = 0; d < 48; ++d) acc += nptr[d] * Wx[d * 48 + h];
    y0[idx] = acc;
  }
  __syncthreads();
  for (int idx = t; idx < 1536; idx += 512) {
    int ci = idx >> 7, o = idx & 127;
    const float* yp = y0 + ci * 48;
    float acc = 0.f;
    for (int h = 0; h < 48; ++h) acc += yp[h] * W1[h * 128 + o];
    s1sh[idx] = acc;
    ws[FB_S1 + idx] = acc;
  }
  for (int idx = blk * 112 + t; idx < (blk + 1) * 112; idx += 512) {
    int op = idx >> 7, o = idx & 127;
    float a1 = ba1[o], a2 = ba2[o];
    for (int d = 0; d < 48; ++d) {
      float e = op_embs[op * 48 + d];
      a1 += e * Wa1[d * 128 + o];
      a2 += e * Wa2[d * 128 + o];
    }
    ws[FB_AT1 + idx] = (op == 0) ? 0.f : sigmoidf_(a1);
    ws[FB_AT2 + idx] = (op == 0) ? 0.f : sigmoidf_(a2);
  }
  __syncthreads();
  for (int idx = blk * 64 + t; idx < (blk + 1) * 64; idx += 512) {
    int c = idx >> 8, i = (idx >> 7) & 1, o = idx & 127;
    const float* sp = s1sh + (c * 6 + i) * 128;
    float acc = 0.f;
    for (int h = 0; h < 128; ++h) acc += fmaxf(sp[h], 0.f) * W2[h * 128 + o];
    ws[FB_S2I + idx] = acc;
  }
}

__global__ __launch_bounds__(256) void main_kernel(
    const int* __restrict__ archs, const float* __restrict__ W2,
    const float* __restrict__ ws, float* __restrict__ out)
{
  const int t  = threadIdx.x;
  const int pp = t >> 6;
  const int o2 = t & 63;
  const int P  = blockIdx.x * 4 + pp;
  const int c  = P & 1;
  __shared__ float y1sh[4][512];
  __shared__ int   archsh[64];
  if (t < 64) archsh[t] = archs[blockIdx.x * 64 + t];
  __syncthreads();
  int f[8], op[8];
  #pragma unroll
  for (int e = 0; e < 8; ++e) { f[e] = archsh[pp * 16 + e]; op[e] = archsh[pp * 16 + 8 + e]; }
  const float2* s1p = (const float2*)ws + c * 384;
  const float2* at1 = (const float2*)(ws + FB_AT1);
  const float2* at2 = (const float2*)(ws + FB_AT2);
  const float2* s2i = (const float2*)(ws + FB_S2I) + c * 128;
  float2 A2[8];
  #pragma unroll
  for (int e = 0; e < 8; ++e) A2[e] = at2[op[e] * 64 + o2];
  float2 S0 = s2i[o2], S1 = s2i[64 + o2];
  #pragma unroll
  for (int i = 0; i < 4; ++i) {
    float2 v = s1p[(2 + i) * 64 + o2];
    int e0 = 2 * i, e1 = 2 * i + 1;
    float2 A0 = at1[op[e0] * 64 + o2];
    float2 B0 = s1p[f[e0] * 64 + o2];
    float2 A1 = at1[op[e1] * 64 + o2];
    float2 B1 = s1p[f[e1] * 64 + o2];
    v.x += A0.x * B0.x + A1.x * B1.x;
    v.y += A0.y * B0.y + A1.y * B1.y;
    ((float2*)(y1sh[pp] + i * 128))[o2] =
        make_float2(fmaxf(v.x, 0.f), fmaxf(v.y, 0.f));
  }
  __syncthreads();
  const float* y1p = y1sh[pp];
  const float2* W2f = (const float2*)W2;
  float ax0 = 0, ax1 = 0, ax2 = 0, ax3 = 0;
  float ay0 = 0, ay1 = 0, ay2 = 0, ay3 = 0;
  for (int h = 0; h < 128; h += 4) {
    float4 q0 = *(const float4*)(y1p + 0 * 128 + h);
    float4 q1 = *(const float4*)(y1p + 1 * 128 + h);
    float4 q2 = *(const float4*)(y1p + 2 * 128 + h);
    float4 q3 = *(const float4*)(y1p + 3 * 128 + h);
    #pragma unroll
    for (int j = 0; j < 4; ++j) {
      float2 wf = W2f[(h + j) * 64 + o2];
      float w0 = wf.x, w1 = wf.y, y;
      y = COMP4(q0, j); ax0 += y * w0; ay0 += y * w1;
      y = COMP4(q1, j); ax1 += y * w0; ay1 += y * w1;
      y = COMP4(q2, j); ax2 += y * w0; ay2 += y * w1;
      y = COMP4(q3, j); ax3 += y * w0; ay3 += y * w1;
    }
  }
  float r0 = ax0 + ax1 + ax2 + ax3;
  float r1 = ay0 + ay1 + ay2 + ay3;
  #pragma unroll
  for (int e = 0; e < 8; ++e) {
    int fe = f[e];
    float sx, sy;
    if (fe == 0)      { sx = S0.x; sy = S0.y; }
    else if (fe == 1) { sx = S1.x; sy = S1.y; }
    else if (fe == 2) { sx = ax0; sy = ay0; }
    else if (fe == 3) { sx = ax1; sy = ay1; }
    else if (fe == 4) { sx = ax2; sy = ay2; }
    else              { sx = ax3; sy = ay3; }
    r0 += A2[e].x * sx;
    r1 += A2[e].y * sy;
  }
  ((float2*)out)[P * 64 + o2] = make_float2(r0 * 0.25f, r1 * 0.25f);
}

extern "C" void kernel_launch(void* const* d_in, const int* in_sizes, int n_in,
                              void* d_out, int out_size, void* d_ws, size_t ws_size,
                              hipStream_t stream) {
  const int* archs = (const int*)d_in[0];
  float* ws = (float*)d_ws;
  if (ws_size >= WS_NEED) {
    config_kernel<<<331, 256, 0, stream>>>(
        (const float*)d_in[1], (const float*)d_in[2], (const float*)d_in[3],
        (const float*)d_in[4], (const float*)d_in[5], (const float*)d_in[6],
        (const float*)d_in[7], (const float*)d_in[8], (const float*)d_in[9],
        (const float*)d_in[10], (const float*)d_in[11], ws);
    gather_kernel<<<NPAIR / 4, 256, 0, stream>>>(archs, ws, (float*)d_out);
  } else {
    precompute_kernel<<<8, 512, 0, stream>>>(
        (const float*)d_in[1], (const float*)d_in[2], (const float*)d_in[3],
        (const float*)d_in[4], (const float*)d_in[5], (const float*)d_in[6],
        (const float*)d_in[7], (const float*)d_in[8], (const float*)d_in[9],
        (const float*)d_in[10], (const float*)d_in[11], ws);
    main_kernel<<<NPAIR / 4, 256, 0, stream>>>(archs, (const float*)d_in[9], ws,
                                               (float*)d_out);
  }
}